// Round 1
// baseline (267.794 us; speedup 1.0000x reference)
//
#include <hip/hip_runtime.h>
#include <hip/hip_bf16.h>
#include <math.h>

#define H_DIM 768
#define E_NUM 8
#define DFF   3072
#define T_NUM 2048
#define PAIRS 4096   // T_NUM * top_k(=2), constant by construction

typedef __attribute__((ext_vector_type(8))) short          s16x8;
typedef __attribute__((ext_vector_type(4))) float          f32x4;
typedef __attribute__((ext_vector_type(4))) unsigned int   u32x4;
typedef __attribute__((ext_vector_type(4))) unsigned short u16x4;

__device__ __forceinline__ unsigned short f2bf(float f) {
  unsigned int u = __builtin_bit_cast(unsigned int, f);
  u += 0x7FFFu + ((u >> 16) & 1u);     // round-to-nearest-even
  return (unsigned short)(u >> 16);
}

__device__ __forceinline__ float gelu_exact(float v) {
  return 0.5f * v * (1.0f + erff(v * 0.70710678118654752f));
}

// ---------------- routing: logits -> softmax -> top2 -> renorm weights ---------------
__global__ void k_route(const float* __restrict__ x, const float* __restrict__ Wg,
                        const float* __restrict__ bg, int* __restrict__ eidx,
                        float* __restrict__ ew, int* __restrict__ counts) {
  int t    = blockIdx.x * 4 + (threadIdx.x >> 6);
  int lane = threadIdx.x & 63;
  float acc[E_NUM];
#pragma unroll
  for (int e = 0; e < E_NUM; ++e) acc[e] = 0.f;
  const float* xr = x + (size_t)t * H_DIM;
#pragma unroll
  for (int i = 0; i < H_DIM / 64; ++i) {
    int h = i * 64 + lane;
    float xv = xr[h];
    const float* wr = Wg + h * E_NUM;
#pragma unroll
    for (int e = 0; e < E_NUM; ++e) acc[e] += xv * wr[e];
  }
#pragma unroll
  for (int e = 0; e < E_NUM; ++e) {
#pragma unroll
    for (int off = 32; off > 0; off >>= 1) acc[e] += __shfl_xor(acc[e], off);
  }
  if (lane == 0) {
    float l[E_NUM];
#pragma unroll
    for (int e = 0; e < E_NUM; ++e) l[e] = acc[e] + bg[e];
    int i0 = 0;
#pragma unroll
    for (int e = 1; e < E_NUM; ++e) if (l[e] > l[i0]) i0 = e;
    int i1 = (i0 == 0) ? 1 : 0;
#pragma unroll
    for (int e = 0; e < E_NUM; ++e) if (e != i0 && l[e] > l[i1]) i1 = e;
    // softmax restricted to {i0,i1} == top-2 softmax renormalized
    float d  = expf(l[i1] - l[i0]);
    eidx[2 * t]     = i0;
    eidx[2 * t + 1] = i1;
    ew[2 * t]       = 1.f / (1.f + d);
    ew[2 * t + 1]   = d / (1.f + d);
    atomicAdd(&counts[i0], 1);
    atomicAdd(&counts[i1], 1);
  }
}

__global__ void k_init(int* __restrict__ ctrl) {
  if (threadIdx.x < 32) ctrl[threadIdx.x] = 0;
}

__global__ void k_scan(const int* __restrict__ counts, int* __restrict__ offsets,
                       int* __restrict__ cursor) {
  if (threadIdx.x == 0) {
    int s = 0;
    for (int e = 0; e < E_NUM; ++e) { offsets[e] = s; cursor[e] = s; s += counts[e]; }
    offsets[E_NUM] = s;
  }
}

__global__ void k_scatter(const int* __restrict__ eidx, int* __restrict__ cursor,
                          int* __restrict__ tok_of, int* __restrict__ slot_of) {
  int t = blockIdx.x * blockDim.x + threadIdx.x;
  if (t >= T_NUM) return;
#pragma unroll
  for (int k = 0; k < 2; ++k) {
    int e = eidx[2 * t + k];
    int s = atomicAdd(&cursor[e], 1);
    tok_of[s] = t;
    slot_of[2 * t + k] = s;
  }
}

// gather x rows (fp32) into slot-ordered bf16 Xg
__global__ void k_gather(const float* __restrict__ x, const int* __restrict__ tok_of,
                         unsigned short* __restrict__ Xg) {
  int s = blockIdx.x;
  int lane = threadIdx.x;
  int t = tok_of[s];
  const f32x4* xr = (const f32x4*)(x + (size_t)t * H_DIM);
  u16x4* orow = (u16x4*)(Xg + (size_t)s * H_DIM);
#pragma unroll
  for (int i = 0; i < H_DIM / 256; ++i) {
    f32x4 v = xr[i * 64 + lane];
    u16x4 o;
    o[0] = f2bf(v[0]); o[1] = f2bf(v[1]); o[2] = f2bf(v[2]); o[3] = f2bf(v[3]);
    orow[i * 64 + lane] = o;
  }
}

// in: [E][R][C] fp32  ->  out: [E][C][R] bf16   (B^T layout for the GEMMs)
__global__ void k_transpose_cast(const float* __restrict__ in, unsigned short* __restrict__ out,
                                 int R, int C) {
  __shared__ float tile[32][33];
  int e  = blockIdx.z;
  int c0 = blockIdx.x * 32, r0 = blockIdx.y * 32;
  int tx = threadIdx.x, ty = threadIdx.y;  // (32, 8)
  const float* ip = in + (size_t)e * R * C;
  unsigned short* op = out + (size_t)e * R * C;
#pragma unroll
  for (int i = 0; i < 4; ++i)
    tile[ty + 8 * i][tx] = ip[(size_t)(r0 + ty + 8 * i) * C + c0 + tx];
  __syncthreads();
#pragma unroll
  for (int i = 0; i < 4; ++i)
    op[(size_t)(c0 + ty + 8 * i) * R + r0 + tx] = f2bf(tile[tx][ty + 8 * i]);
}

// m97-style 128x128 tile GEMM, A [slots][KDIM] bf16, B^T [E][NDIM][KDIM] bf16.
// Per-expert segment rows [offsets[e], offsets[e]+counts[e]); edge tiles clamp
// A-row loads and predicate stores. GELU_OUT: gelu -> bf16 store; else bias+fp32.
template <int KDIM, int NDIM, bool GELU_OUT>
__global__ __launch_bounds__(256) void k_gemm(
    const unsigned short* __restrict__ A, const unsigned short* __restrict__ B,
    const float* __restrict__ bias, void* __restrict__ C,
    const int* __restrict__ counts, const int* __restrict__ offsets) {
  int e  = blockIdx.z;
  int Me = counts[e];
  int mt = blockIdx.y;
  if (mt * 128 >= Me) return;
  int nt  = blockIdx.x;
  int seg = offsets[e];

  __shared__ __align__(16) unsigned short Al[128 * 64];
  __shared__ __align__(16) unsigned short Bl[128 * 64];

  int tid  = threadIdx.x;
  int lane = tid & 63;
  int wave = tid >> 6;
  int wm = wave >> 1, wn = wave & 1;   // 2x2 waves, 64x64 each

  int sr = tid >> 3;          // staging row 0..31
  int sc = (tid & 7) * 8;     // staging col (elems)

  f32x4 acc[4][4];
#pragma unroll
  for (int m = 0; m < 4; ++m)
#pragma unroll
    for (int n = 0; n < 4; ++n) acc[m][n] = (f32x4){0.f, 0.f, 0.f, 0.f};

  const unsigned short* Bbase = B + (size_t)e * NDIM * KDIM + (size_t)(nt * 128) * KDIM;

  for (int k0 = 0; k0 < KDIM; k0 += 64) {
#pragma unroll
    for (int j = 0; j < 4; ++j) {
      int r = mt * 128 + j * 32 + sr;
      r = (r < Me) ? r : (Me - 1);     // clamp (dup last row; stores predicated)
      const unsigned short* gp = A + (size_t)(seg + r) * KDIM + k0 + sc;
      __builtin_amdgcn_global_load_lds(
          (__attribute__((address_space(1))) void*)gp,
          (__attribute__((address_space(3))) void*)&Al[(j * 32 + sr) * 64 + sc], 16, 0, 0);
    }
#pragma unroll
    for (int j = 0; j < 4; ++j) {
      const unsigned short* gp = Bbase + (size_t)(j * 32 + sr) * KDIM + k0 + sc;
      __builtin_amdgcn_global_load_lds(
          (__attribute__((address_space(1))) void*)gp,
          (__attribute__((address_space(3))) void*)&Bl[(j * 32 + sr) * 64 + sc], 16, 0, 0);
    }
    __syncthreads();   // compiler emits vmcnt(0) drain before barrier

#pragma unroll
    for (int kk = 0; kk < 2; ++kk) {
      int ko = kk * 32 + (lane >> 4) * 8;
      s16x8 af[4], bfr[4];
#pragma unroll
      for (int m = 0; m < 4; ++m) {
        u32x4 v = *(const u32x4*)&Al[(wm * 64 + m * 16 + (lane & 15)) * 64 + ko];
        af[m] = __builtin_bit_cast(s16x8, v);
      }
#pragma unroll
      for (int n = 0; n < 4; ++n) {
        u32x4 v = *(const u32x4*)&Bl[(wn * 64 + n * 16 + (lane & 15)) * 64 + ko];
        bfr[n] = __builtin_bit_cast(s16x8, v);
      }
#pragma unroll
      for (int m = 0; m < 4; ++m)
#pragma unroll
        for (int n = 0; n < 4; ++n)
          acc[m][n] = __builtin_amdgcn_mfma_f32_16x16x32_bf16(af[m], bfr[n], acc[m][n], 0, 0, 0);
    }
    __syncthreads();
  }

  // epilogue: C/D layout col = lane&15, row = (lane>>4)*4 + reg
  int rbase = mt * 128 + wm * 64;
#pragma unroll
  for (int m = 0; m < 4; ++m) {
#pragma unroll
    for (int n = 0; n < 4; ++n) {
      int col = nt * 128 + wn * 64 + n * 16 + (lane & 15);
      float bv = bias[e * NDIM + col];
#pragma unroll
      for (int r = 0; r < 4; ++r) {
        int row = rbase + m * 16 + (lane >> 4) * 4 + r;
        if (row < Me) {
          float v = acc[m][n][r] + bv;
          size_t idx = (size_t)(seg + row) * NDIM + col;
          if constexpr (GELU_OUT) {
            ((unsigned short*)C)[idx] = f2bf(gelu_exact(v));
          } else {
            ((float*)C)[idx] = v;
          }
        }
      }
    }
  }
}

// out[t] = w0 * Eo[slot0] + w1 * Eo[slot1]
__global__ void k_combine(const float* __restrict__ Eo, const int* __restrict__ slot_of,
                          const float* __restrict__ ew, float* __restrict__ out) {
  int t = blockIdx.x;
  int i = threadIdx.x;  // 192 threads * float4 = 768
  int s0 = slot_of[2 * t], s1 = slot_of[2 * t + 1];
  float w0 = ew[2 * t], w1 = ew[2 * t + 1];
  const f32x4* a = (const f32x4*)(Eo + (size_t)s0 * H_DIM);
  const f32x4* b = (const f32x4*)(Eo + (size_t)s1 * H_DIM);
  f32x4 va = a[i], vb = b[i];
  f32x4 o;
  o[0] = w0 * va[0] + w1 * vb[0];
  o[1] = w0 * va[1] + w1 * vb[1];
  o[2] = w0 * va[2] + w1 * vb[2];
  o[3] = w0 * va[3] + w1 * vb[3];
  ((f32x4*)(out + (size_t)t * H_DIM))[i] = o;
}

extern "C" void kernel_launch(void* const* d_in, const int* in_sizes, int n_in,
                              void* d_out, int out_size, void* d_ws, size_t ws_size,
                              hipStream_t stream) {
  (void)in_sizes; (void)n_in; (void)out_size;
  const float* x  = (const float*)d_in[0];
  const float* Wg = (const float*)d_in[1];
  const float* bg = (const float*)d_in[2];
  const float* W1 = (const float*)d_in[3];
  const float* b1 = (const float*)d_in[4];
  const float* W2 = (const float*)d_in[5];
  const float* b2 = (const float*)d_in[6];
  float* out = (float*)d_out;

  char* w = (char*)d_ws;
  size_t off = 0;
  auto take = [&](size_t n) { void* p = w + off; off = (off + n + 255) & ~(size_t)255; return p; };
  int*   ctrl    = (int*)  take(64 * sizeof(int));     // [0..7] counts, [8..15] cursor, [16..24] offsets
  int*   eidx    = (int*)  take(PAIRS * sizeof(int));
  float* ew      = (float*)take(PAIRS * sizeof(float));
  int*   slot_of = (int*)  take(PAIRS * sizeof(int));
  int*   tok_of  = (int*)  take(PAIRS * sizeof(int));
  unsigned short* Xg   = (unsigned short*)take((size_t)PAIRS * H_DIM * 2);
  unsigned short* Wb   = (unsigned short*)take((size_t)E_NUM * H_DIM * DFF * 2);  // reused W1b then W2b
  unsigned short* Hmid = (unsigned short*)take((size_t)PAIRS * DFF * 2);
  float* Eo            = (float*)take((size_t)PAIRS * H_DIM * sizeof(float));
  if (off > ws_size) return;  // recognizable failure mode: output stays zero

  int* counts  = ctrl;
  int* cursor  = ctrl + 8;
  int* offsets = ctrl + 16;

  k_init<<<1, 64, 0, stream>>>(ctrl);
  k_route<<<T_NUM / 4, 256, 0, stream>>>(x, Wg, bg, eidx, ew, counts);
  k_scan<<<1, 64, 0, stream>>>(counts, offsets, cursor);
  k_scatter<<<T_NUM / 256, 256, 0, stream>>>(eidx, cursor, tok_of, slot_of);
  k_gather<<<PAIRS, 64, 0, stream>>>(x, tok_of, Xg);

  // W1 [E][768][3072] -> Wb [E][3072][768] bf16
  k_transpose_cast<<<dim3(DFF / 32, H_DIM / 32, E_NUM), dim3(32, 8), 0, stream>>>(W1, Wb, H_DIM, DFF);
  k_gemm<H_DIM, DFF, true><<<dim3(DFF / 128, 16, E_NUM), 256, 0, stream>>>(
      Xg, Wb, b1, Hmid, counts, offsets);

  // W2 [E][3072][768] -> Wb [E][768][3072] bf16 (reuse; stream order serializes)
  k_transpose_cast<<<dim3(H_DIM / 32, DFF / 32, E_NUM), dim3(32, 8), 0, stream>>>(W2, Wb, DFF, H_DIM);
  k_gemm<DFF, H_DIM, false><<<dim3(H_DIM / 128, 16, E_NUM), 256, 0, stream>>>(
      Hmid, Wb, b2, Eo, counts, offsets);

  k_combine<<<T_NUM, 192, 0, stream>>>(Eo, slot_of, ew, out);
}